// Round 1
// baseline (247.865 us; speedup 1.0000x reference)
//
#include <hip/hip_runtime.h>
#include <math.h>

// NetVLAD: N=32, C=512, H=W=32 (P=1024), K=64, ALPHA=100, EPS=1e-12
#define ALPHA 100.0f
#define EPSN 1e-12f

// ---------------- prep: vt[c][k] = v[k][c]; bias[k] = -alpha*||v_k|| --------
__global__ __launch_bounds__(64) void prep_kernel(const float* __restrict__ v,
                                                  float* __restrict__ vt,
                                                  float* __restrict__ bias) {
    int k = blockIdx.x;      // 0..63
    int lane = threadIdx.x;  // 0..63
    const float* row = v + k * 512;
    float ssq = 0.f;
#pragma unroll
    for (int i = 0; i < 8; ++i) {
        float xv = row[lane + 64 * i];
        ssq = fmaf(xv, xv, ssq);
    }
#pragma unroll
    for (int off = 32; off > 0; off >>= 1) ssq += __shfl_xor(ssq, off, 64);
    if (lane == 0) bias[k] = -ALPHA * sqrtf(ssq);
    for (int c = lane; c < 512; c += 64) vt[c * 64 + k] = row[c];
}

// ---------------- assign: logits -> softmax a[n][p][k], s_inv, asum ---------
// block = 256 = 64 p-positions x 4 k-groups(16 k each). grid = 512.
__global__ __launch_bounds__(256) void assign_kernel(
    const float* __restrict__ x, const float* __restrict__ vt,
    const float* __restrict__ bias, float* __restrict__ a,
    float* __restrict__ asum, float* __restrict__ s_inv) {
    int tid = threadIdx.x;
    int lane = tid & 63;
    int w = tid >> 6;
    int kg16 = __builtin_amdgcn_readfirstlane(w << 4);  // 0,16,32,48 (SGPR)
    int g = blockIdx.x * 64 + lane;  // global descriptor id, 0..32767
    int n = g >> 10;
    const float* xp = x + (size_t)n * 524288 + (g & 1023);  // + c*1024

    float acc[16];
#pragma unroll
    for (int j = 0; j < 16; ++j) acc[j] = 0.f;
    float ssq = 0.f;
    const float* vrow = vt + kg16;
#pragma unroll 4
    for (int c = 0; c < 512; ++c) {
        float xv = xp[(size_t)c << 10];           // coalesced (lane = p)
        ssq = fmaf(xv, xv, ssq);
        const float* vr = vrow + (c << 6);        // wave-uniform -> s_load
#pragma unroll
        for (int j = 0; j < 16; ++j) acc[j] = fmaf(xv, vr[j], acc[j]);
    }
    float sinv = 1.0f / fmaxf(sqrtf(ssq), EPSN);
    if (w == 0) s_inv[g] = sinv;

    // logits + local max
    float m = -INFINITY;
    float twoAs = 2.0f * ALPHA * sinv;
#pragma unroll
    for (int j = 0; j < 16; ++j) {
        acc[j] = fmaf(twoAs, acc[j], bias[kg16 + j]);
        m = fmaxf(m, acc[j]);
    }
    __shared__ float red[4][64];
    red[w][lane] = m;
    __syncthreads();
    m = fmaxf(fmaxf(red[0][lane], red[1][lane]),
              fmaxf(red[2][lane], red[3][lane]));
    __syncthreads();
    float s = 0.f;
#pragma unroll
    for (int j = 0; j < 16; ++j) {
        acc[j] = expf(acc[j] - m);
        s += acc[j];
    }
    red[w][lane] = s;
    __syncthreads();
    s = red[0][lane] + red[1][lane] + red[2][lane] + red[3][lane];
    float rs = 1.0f / s;
#pragma unroll
    for (int j = 0; j < 16; ++j) acc[j] *= rs;

    float4* ap = (float4*)(a + (size_t)g * 64 + kg16);
    ap[0] = make_float4(acc[0], acc[1], acc[2], acc[3]);
    ap[1] = make_float4(acc[4], acc[5], acc[6], acc[7]);
    ap[2] = make_float4(acc[8], acc[9], acc[10], acc[11]);
    ap[3] = make_float4(acc[12], acc[13], acc[14], acc[15]);

    // asum[n][k] += sum_p a  (reduce over the 64 lanes = 64 p's)
#pragma unroll
    for (int j = 0; j < 16; ++j) {
        float v = acc[j];
#pragma unroll
        for (int off = 32; off > 0; off >>= 1) v += __shfl_xor(v, off, 64);
        if (lane == 0) atomicAdd(&asum[n * 64 + kg16 + j], v);
    }
}

// ---------------- vlad: out_raw[n][k][c] = sum_p a[n][p][k]*x[n][c][p]*sinv -
// grid (8 ctiles, 32 n), block 256. 64k x 64c per block, p chunked by 64.
__global__ __launch_bounds__(256) void vlad_kernel(
    const float* __restrict__ x, const float* __restrict__ a,
    const float* __restrict__ s_inv, float* __restrict__ out) {
    int n = blockIdx.y;
    int c_blk = blockIdx.x * 64;
    int tid = threadIdx.x;
    int k0 = (tid >> 4) * 4;  // consecutive lanes -> consecutive c (stores)
    int c0 = (tid & 15) * 4;

    __shared__ __align__(16) float at[64][64];  // [p][k]
    __shared__ float xt[64][65];                // [c][p] (+1 pad)

    float acc[4][4];
#pragma unroll
    for (int i = 0; i < 4; ++i)
#pragma unroll
        for (int j = 0; j < 4; ++j) acc[i][j] = 0.f;

    const float* abase = a + (size_t)n * 1024 * 64;
    const float* xbase = x + (size_t)n * 524288 + (size_t)c_blk * 1024;
    const float* sbase = s_inv + n * 1024;

    for (int pc = 0; pc < 16; ++pc) {
        __syncthreads();
        const float4* a4 = (const float4*)(abase + pc * 4096);
#pragma unroll
        for (int i = 0; i < 4; ++i) {
            int f = tid + i * 256;  // 0..1023 float4s
            float4 val = a4[f];
            *(float4*)&at[f >> 4][(f & 15) * 4] = val;
        }
        int pp = tid & 63;
        int r0 = tid >> 6;
        float sv = sbase[pc * 64 + pp];
#pragma unroll
        for (int i = 0; i < 16; ++i) {
            int cr = r0 + i * 4;
            xt[cr][pp] = xbase[(size_t)cr * 1024 + pc * 64 + pp] * sv;
        }
        __syncthreads();
#pragma unroll 4
        for (int p = 0; p < 64; ++p) {
            float4 av = *(const float4*)&at[p][k0];
            float xv[4];
#pragma unroll
            for (int j = 0; j < 4; ++j) xv[j] = xt[c0 + j][p];
#pragma unroll
            for (int j = 0; j < 4; ++j) {
                acc[0][j] = fmaf(av.x, xv[j], acc[0][j]);
                acc[1][j] = fmaf(av.y, xv[j], acc[1][j]);
                acc[2][j] = fmaf(av.z, xv[j], acc[2][j]);
                acc[3][j] = fmaf(av.w, xv[j], acc[3][j]);
            }
        }
    }
    float* obase = out + (size_t)n * 32768 + c_blk;
#pragma unroll
    for (int i = 0; i < 4; ++i) {
        int k = k0 + i;
        *(float4*)&obase[(size_t)k * 512 + c0] =
            make_float4(acc[i][0], acc[i][1], acc[i][2], acc[i][3]);
    }
}

// ---------------- norm: apply -asum*v, intra-norm per k, global norm per n --
__global__ __launch_bounds__(256) void norm_kernel(float* __restrict__ out,
                                                   const float* __restrict__ v,
                                                   const float* __restrict__ asum) {
    int n = blockIdx.x;
    int tid = threadIdx.x;
    int lane = tid & 63, w = tid >> 6;
    __shared__ float scale[64];
    __shared__ float asml[64];
    __shared__ float tot[4];
    float* base = out + (size_t)n * 32768;
    if (tid < 64) asml[tid] = asum[n * 64 + tid];
    __syncthreads();
    float ptot = 0.f;
    for (int k = w; k < 64; k += 4) {  // wave w handles 16 rows
        float as = asml[k];
        const float* r = base + k * 512;
        const float* vr = v + k * 512;
        float ssq = 0.f;
#pragma unroll
        for (int i = 0; i < 8; ++i) {
            float val = fmaf(-as, vr[lane + i * 64], r[lane + i * 64]);
            ssq = fmaf(val, val, ssq);
        }
#pragma unroll
        for (int off = 32; off > 0; off >>= 1) ssq += __shfl_xor(ssq, off, 64);
        float nk = sqrtf(ssq);
        float inv = 1.0f / fmaxf(nk, EPSN);
        float t = nk * inv;
        ptot += t * t;
        if (lane == 0) scale[k] = inv;
    }
    if (lane == 0) tot[w] = ptot;
    __syncthreads();
    float total = sqrtf(tot[0] + tot[1] + tot[2] + tot[3]);
    float invt = 1.0f / fmaxf(total, EPSN);
    for (int idx = tid; idx < 32768; idx += 256) {
        int k = idx >> 9;
        float val = fmaf(-asml[k], v[idx], base[idx]);  // v[k*512+c] == v[idx]
        base[idx] = val * scale[k] * invt;
    }
}

extern "C" void kernel_launch(void* const* d_in, const int* in_sizes, int n_in,
                              void* d_out, int out_size, void* d_ws, size_t ws_size,
                              hipStream_t stream) {
    const float* x = (const float*)d_in[0];       // [32,512,32,32]
    const float* vocabs = (const float*)d_in[1];  // [64,512]
    float* out = (float*)d_out;                   // [32, 32768]
    char* ws = (char*)d_ws;
    float* vt   = (float*)(ws);             // 131072 B : vocab^T [c][k]
    float* bias = (float*)(ws + 131072);    //    256 B
    float* asum = (float*)(ws + 131328);    //   8192 B
    float* sinv = (float*)(ws + 139520);    // 131072 B
    float* a    = (float*)(ws + 270592);    // 8 MB : a[n][p][k]

    hipMemsetAsync(asum, 0, 8192, stream);
    prep_kernel<<<64, 64, 0, stream>>>(vocabs, vt, bias);
    assign_kernel<<<512, 256, 0, stream>>>(x, vt, bias, a, asum, sinv);
    vlad_kernel<<<dim3(8, 32), 256, 0, stream>>>(x, a, sinv, out);
    norm_kernel<<<32, 256, 0, stream>>>(out, vocabs, asum);
}